// Round 8
// baseline (394.465 us; speedup 1.0000x reference)
//
#include <hip/hip_runtime.h>
#include <hip/hip_bf16.h>
#include <stdint.h>

#define B_   2048
#define P_   20
#define D_   64
#define V_   100000
#define T_   33
#define FIN  2240          // 35*64
#define KE   2112          // 33*64  (emb-only K; raw cols folded into epilogue)
#define M_   (B_*P_)       // 40960
#define H1_  512
#define H2_  256
#define NKT  33            // K-tiles of 64

using bf16 = __hip_bfloat16;
typedef __bf16 bf16x8 __attribute__((ext_vector_type(8)));
typedef float  f32x4  __attribute__((ext_vector_type(4)));

__device__ __forceinline__ void gload16(const void* g, void* l) {
    __builtin_amdgcn_global_load_lds(
        (const __attribute__((address_space(1))) uint32_t*)g,
        (__attribute__((address_space(3))) uint32_t*)l, 16, 0, 0);
}
__device__ __forceinline__ void gload4(const void* g, void* l) {
    __builtin_amdgcn_global_load_lds(
        (const __attribute__((address_space(1))) uint32_t*)g,
        (__attribute__((address_space(3))) uint32_t*)l, 4, 0, 0);
}
__device__ __forceinline__ unsigned short b16bits(float f) {
    return __builtin_bit_cast(unsigned short, __float2bfloat16(f));
}

// ---------------------------------------------------------------------------
// prep 1: column sums of W1 rows 0..63 (S0) and 64..127 (S1).  S01 = [S0|S1]
// ---------------------------------------------------------------------------
__global__ __launch_bounds__(256) void colsum_k(
    const float* __restrict__ W1, float* __restrict__ S01)
{
    int g = blockIdx.x * 256 + threadIdx.x;   // 0..1023
    int s = g >> 9, n = g & 511;
    const float* p = W1 + (size_t)(s * 64) * H1_ + n;
    float acc = 0.f;
    #pragma unroll 8
    for (int k = 0; k < 64; ++k) acc += p[(size_t)k * H1_];
    S01[s * H1_ + n] = acc;
}

// ---------------------------------------------------------------------------
// prep 2: W1 rows 128.. -> W1t (512 x 2112) bf16 row-major (transposed)
// ---------------------------------------------------------------------------
__global__ __launch_bounds__(256) void w1t_k(
    const float* __restrict__ W1, bf16* __restrict__ W1t)
{
    int idx = blockIdx.x * 256 + threadIdx.x;   // n*KE + k
    int n = idx / KE;
    int k = idx - n * KE;
    W1t[idx] = __float2bfloat16(W1[(size_t)(k + 128) * H1_ + n]);
}

// ---------------------------------------------------------------------------
// prep 3: generic W (K x N fp32) -> Wt (N x K bf16)
// ---------------------------------------------------------------------------
__global__ __launch_bounds__(256) void transpose_bf16_k(
    const float* __restrict__ W, bf16* __restrict__ Wt, int K, int N)
{
    int idx = blockIdx.x * 256 + threadIdx.x;
    if (idx >= N * K) return;
    int n = idx / K;
    int k = idx - n * K;
    Wt[idx] = __float2bfloat16(W[(size_t)k * N + n]);
}

// ---------------------------------------------------------------------------
// FUSED gather + GEMM1 (v8): BM=320, BN=256 — halves B traffic vs R5.
//   grid 256: mt=(bid&7)|((bid>>4)<<3), nt=(bid>>3)&1 -> N-pair of each
//   M-tile lands on one XCD (bids b, b+8) so the duplicated A-gather L2-hits.
//   8 waves, wave grid 4Mx2N, wave tile 80x128, acc[5][8] (160 VGPR).
//   A: reg-staged bf16 (2 batches x 5 dwordx4/wave), dbuf 2x40KB LDS.
//      Batches consumed ~0.8/0.4 iter after issue -> compiler auto-waits
//      are benign (ledger-verified vmcnt(8)/vmcnt(2)).
//   B: 2 K-halves of 16KB, ping-pong, manual vmcnt(8)/vmcnt(13).
//   idx: proven LDS ring (slot = t&1), depth 2.
// ---------------------------------------------------------------------------
__global__ __launch_bounds__(512, 2) void fused_gemm1_k(
    const float* __restrict__ x_raw, const int* __restrict__ x_idx,
    const float* __restrict__ emb, const bf16* __restrict__ W1t,
    const float* __restrict__ b1, const float* __restrict__ S01,
    bf16* __restrict__ h1)
{
    extern __shared__ char smem[];
    char* Als  = smem;                  // 2 x [320 rows][128B bf16] = 81920
    char* Bls  = smem + 81920;          // 2 halves x [256 rows][64B] = 32768
    char* ring = smem + 81920 + 32768;  // 2 slots x 8 waves x 160B  = 2560

    const int tid = threadIdx.x;
    const int w  = tid >> 6, l = tid & 63;
    const int wr = w >> 1, wc = w & 1;          // 4 x 2 wave grid
    const int fr = l & 15, fq = l >> 4;

    const int bid = blockIdx.x;
    const int mt  = (bid & 7) | ((bid >> 4) << 3);
    const int nt  = (bid >> 3) & 1;
    const int m0  = mt * 320;
    const int n0  = nt * 256;

    const int arsub = l >> 4;                   // 0..3 (A: 4 rows/instr)
    const int acol  = l & 15;                   // 16B unit (fp32 src)
    const int brsub = l >> 2;                   // 0..15 (B: 16 rows/instr)
    const int bcol  = l & 3;

    f32x4  acc[5][8] = {};
    float4 aA[5], aB[5];                        // two named reg batches
    int    ivA[5], ivB[5];

    auto issue_idx = [&](int t) {               // idx(t) -> slot t&1
        if (l < 40)
            gload4((const char*)x_idx + ((size_t)(m0 + w * 40 + l) * T_ + t) * 4,
                   ring + (t & 1) * 1280 + w * 160);
    };
    auto read_iv = [&](int t, int b, int (&iv)[5]) {
        const int* ivp = (const int*)(ring + (t & 1) * 1280 + w * 160);
        #pragma unroll
        for (int p = 0; p < 5; ++p) iv[p] = ivp[b * 20 + p * 4 + arsub];
    };
    auto issue_aregs = [&](int t, const int (&iv)[5], float4 (&ar)[5]) {
        #pragma unroll
        for (int p = 0; p < 5; ++p)
            ar[p] = *reinterpret_cast<const float4*>(
                emb + ((size_t)t * V_ + (size_t)iv[p]) * D_ + acol * 4);
    };
    auto write_A = [&](int buf, int b, const float4 (&ar)[5]) {
        char* base = Als + buf * 40960;
        #pragma unroll
        for (int p = 0; p < 5; ++p) {
            int row = w * 40 + b * 20 + p * 4 + arsub;
            ushort4 o;
            o.x = b16bits(ar[p].x); o.y = b16bits(ar[p].y);
            o.z = b16bits(ar[p].z); o.w = b16bits(ar[p].w);
            int byte = (row * 128 + acol * 8) ^ ((row & 7) << 4);
            *reinterpret_cast<ushort4*>(base + byte) = o;
        }
    };
    auto issue_B = [&](int t, int h) {          // 2 instr/wave per half
        char* dst = Bls + h * 16384 + w * 2048;
        #pragma unroll
        for (int i = 0; i < 2; ++i) {
            int row = w * 32 + i * 16 + brsub;
            const char* src = (const char*)W1t
                + ((size_t)(n0 + row) * KE + t * 64 + h * 32) * 2
                + ((bcol * 16) ^ ((row & 3) << 4));
            gload16(src, dst + i * 1024);
        }
    };
    auto mfma_half = [&](int abuf, int kk) {
        const char* Ab = Als + abuf * 40960;
        bf16x8 af[5];
        #pragma unroll
        for (int i = 0; i < 5; ++i) {
            int r = wr * 80 + i * 16 + fr;
            af[i] = *(const bf16x8*)(Ab + ((r * 128 + kk * 64 + fq * 16)
                                           ^ ((r & 7) << 4)));
        }
        const char* Bb = Bls + kk * 16384;
        #pragma unroll
        for (int j = 0; j < 8; ++j) {
            int n = wc * 128 + j * 16 + fr;
            bf16x8 bg = *(const bf16x8*)(Bb + n * 64 + ((fq * 16) ^ ((n & 3) << 4)));
            #pragma unroll
            for (int i = 0; i < 5; ++i)
                acc[i][j] = __builtin_amdgcn_mfma_f32_16x16x32_bf16(
                    af[i], bg, acc[i][j], 0, 0, 0);
        }
    };

    // ---- prologue -------------------------------------------------------
    issue_idx(0);
    asm volatile("s_waitcnt vmcnt(0)" ::: "memory");
    read_iv(0, 0, ivA);
    read_iv(0, 1, ivB);
    issue_aregs(0, ivA, aA);
    issue_aregs(0, ivB, aB);
    asm volatile("s_waitcnt vmcnt(0)" ::: "memory");
    write_A(0, 0, aA);
    write_A(0, 1, aB);
    issue_idx(1);                                   // +1
    issue_B(0, 0);                                  // +2
    issue_B(0, 1);                                  // +2
    asm volatile("s_waitcnt vmcnt(4)" ::: "memory"); // idx(1) done
    read_iv(1, 0, ivA);
    read_iv(1, 1, ivB);
    // ledger entering loop: [Bh0(0) 2, Bh1(0) 2]

    // ---- main loop ------------------------------------------------------
    for (int kt = 0; kt < NKT; ++kt) {
        int tA = (kt + 1 < NKT) ? kt + 1 : NKT - 1;   // clamped tails keep
        int t2 = (kt + 2 < NKT) ? kt + 2 : NKT - 1;   // counts uniform

        issue_aregs(tA, ivA, aA);                     // +5 (batch0, buf^1)
        issue_idx(t2);                                // +1
        asm volatile("s_waitcnt vmcnt(8)" ::: "memory");   // Bh0(kt) done
        asm volatile("s_waitcnt lgkmcnt(0)" ::: "memory"); // A writes visible
        __builtin_amdgcn_s_barrier();
        __builtin_amdgcn_sched_barrier(0);

        __builtin_amdgcn_s_setprio(1);
        mfma_half(kt & 1, 0);
        __builtin_amdgcn_s_setprio(0);
        asm volatile("s_waitcnt lgkmcnt(0)" ::: "memory");
        __builtin_amdgcn_s_barrier();

        issue_B(tA, 0);                               // +2 (overwrite Bh0)
        issue_aregs(tA, ivB, aB);                     // +5 (batch1, buf^1)
        asm volatile("s_waitcnt vmcnt(13)" ::: "memory");  // Bh1(kt) done
        __builtin_amdgcn_s_barrier();
        __builtin_amdgcn_sched_barrier(0);

        __builtin_amdgcn_s_setprio(1);
        mfma_half(kt & 1, 1);
        __builtin_amdgcn_s_setprio(0);
        asm volatile("s_waitcnt lgkmcnt(0)" ::: "memory");
        __builtin_amdgcn_s_barrier();

        write_A(kt & 1 ^ 1, 0, aA);   // auto-wait ~vmcnt(8): aA ~0.8 iter old
        issue_B(tA, 1);               // +2 (overwrite Bh1)
        write_A(kt & 1 ^ 1, 1, aB);   // auto-wait ~vmcnt(2): drains aB, idx,
                                      // Bh0(kt+1) (all >=0.4 iter old)
        read_iv(t2, 0, ivA);          // iv for next iter's issues
        read_iv(t2, 1, ivB);
        // ledger at end: [Bh1(kt+1) 2]
    }
    asm volatile("s_waitcnt vmcnt(0)" ::: "memory");  // drain clamped junk

    // ---- epilogue: bias + rank-2 raw contribution + relu -> h1 ---------
    const float* S0 = S01;
    const float* S1 = S01 + H1_;
    #pragma unroll
    for (int i = 0; i < 5; ++i) {
        int rbase = wr * 80 + i * 16 + fq * 4;
        float x0[4], x1[4];
        #pragma unroll
        for (int r2 = 0; r2 < 4; ++r2) {
            int m = m0 + rbase + r2;
            x0[r2] = x_raw[2 * m];
            x1[r2] = x_raw[2 * m + 1];
        }
        #pragma unroll
        for (int j = 0; j < 8; ++j) {
            int n = n0 + wc * 128 + j * 16 + fr;
            float bb = b1[n], s0 = S0[n], s1 = S1[n];
            #pragma unroll
            for (int r2 = 0; r2 < 4; ++r2) {
                float v = acc[i][j][r2] + bb + x0[r2] * s0 + x1[r2] * s1;
                h1[(size_t)(m0 + rbase + r2) * H1_ + n] =
                    __float2bfloat16(fmaxf(v, 0.0f));
            }
        }
    }
}

// ---------------------------------------------------------------------------
// FUSED GEMM2 + head (R3/R5-proven):  h2 = relu(h1 @ W2 + b2);
// logits = h2 @ W3 + b3; softmax over P=20.  BM=160 (=8 batches), BN=256.
// ---------------------------------------------------------------------------
__global__ __launch_bounds__(512) void gemm2_head_k(
    const bf16* __restrict__ h1, const bf16* __restrict__ W2t,
    const float* __restrict__ b2, const float* __restrict__ W3,
    const float* __restrict__ b3, float* __restrict__ out)
{
    __shared__ char  As[20480];       // [160][64] bf16 swizzled
    __shared__ char  Bs[32768];       // [256][64] bf16 swizzled
    __shared__ float w3s[H2_];
    __shared__ float b2s[H2_];
    __shared__ float logq[4][160];
    __shared__ float logits[160];

    const int tid = threadIdx.x;
    const int w = tid >> 6, l = tid & 63;
    const int wr = w >> 2, wc = w & 3;
    const int fr = l & 15, fq = l >> 4;
    const int m0 = blockIdx.x * 160;
    const int r8 = l >> 3, c8 = l & 7;

    if (tid < H2_) { w3s[tid] = W3[tid]; b2s[tid] = b2[tid]; }

    f32x4 acc[5][4] = {};

    for (int kt = 0; kt < 8; ++kt) {
        for (int s = w; s < 20; s += 8) {
            int row = s * 8 + r8;
            const char* src = (const char*)(h1 + (size_t)(m0 + row) * H1_ + kt * 64)
                              + ((16 * c8) ^ ((row & 7) << 4));
            gload16(src, As + s * 1024);
        }
        #pragma unroll
        for (int q = 0; q < 4; ++q) {
            int s = q * 8 + w;
            int row = s * 8 + r8;
            const char* src = (const char*)(W2t + (size_t)row * H1_ + kt * 64)
                              + ((16 * c8) ^ ((row & 7) << 4));
            gload16(src, Bs + s * 1024);
        }
        __syncthreads();

        #pragma unroll
        for (int kk = 0; kk < 2; ++kk) {
            bf16x8 af[5];
            #pragma unroll
            for (int i = 0; i < 5; ++i) {
                int r = wr * 80 + i * 16 + fr;
                int byte = (r * 128 + kk * 64 + fq * 16) ^ ((r & 7) << 4);
                af[i] = *(const bf16x8*)(As + byte);
            }
            #pragma unroll
            for (int j = 0; j < 4; ++j) {
                int n = wc * 64 + j * 16 + fr;
                int byte = (n * 128 + kk * 64 + fq * 16) ^ ((n & 7) << 4);
                bf16x8 bg = *(const bf16x8*)(Bs + byte);
                #pragma unroll
                for (int i = 0; i < 5; ++i)
                    acc[i][j] = __builtin_amdgcn_mfma_f32_16x16x32_bf16(
                        af[i], bg, acc[i][j], 0, 0, 0);
            }
        }
        __syncthreads();
    }

    #pragma unroll
    for (int i = 0; i < 5; ++i) {
        #pragma unroll
        for (int r2 = 0; r2 < 4; ++r2) {
            float s = 0.f;
            #pragma unroll
            for (int j = 0; j < 4; ++j) {
                int col = wc * 64 + j * 16 + fr;
                float v = fmaxf(acc[i][j][r2] + b2s[col], 0.f);
                s += v * w3s[col];
            }
            #pragma unroll
            for (int off = 1; off < 16; off <<= 1) s += __shfl_xor(s, off);
            if (fr == 0)
                logq[wc][wr * 80 + i * 16 + fq * 4 + r2] = s;
        }
    }
    __syncthreads();
    if (tid < 160)
        logits[tid] = logq[0][tid] + logq[1][tid] + logq[2][tid] + logq[3][tid] + b3[0];
    __syncthreads();
    if (tid < 160) {
        int bb = (tid / 20) * 20;
        float mx = -1e30f;
        #pragma unroll
        for (int p = 0; p < 20; ++p) mx = fmaxf(mx, logits[bb + p]);
        float sum = 0.f;
        #pragma unroll
        for (int p = 0; p < 20; ++p) sum += expf(logits[bb + p] - mx);
        out[m0 + tid] = expf(logits[tid] - mx) / sum;
    }
}

// ---------------------------------------------------------------------------
extern "C" void kernel_launch(void* const* d_in, const int* in_sizes, int n_in,
                              void* d_out, int out_size, void* d_ws, size_t ws_size,
                              hipStream_t stream)
{
    const float* x_raw = (const float*)d_in[0];
    const int*   x_idx = (const int*)  d_in[1];
    const float* emb   = (const float*)d_in[2];
    const float* W1    = (const float*)d_in[3];
    const float* b1    = (const float*)d_in[4];
    const float* W2    = (const float*)d_in[5];
    const float* b2    = (const float*)d_in[6];
    const float* W3    = (const float*)d_in[7];
    const float* b3    = (const float*)d_in[8];

    char* ws = (char*)d_ws;
    size_t off = 0;
    bf16*  W1t = (bf16*) (ws + off); off += (size_t)H1_ * KE * 2;    // 2.16 MB
    bf16*  W2t = (bf16*) (ws + off); off += (size_t)H2_ * H1_ * 2;   // 0.26 MB
    float* S01 = (float*)(ws + off); off += (size_t)2 * H1_ * 4;     // 4 KB
    bf16*  h1  = (bf16*) (ws + off); off += (size_t)M_ * H1_ * 2;    // 42 MB

    // prep
    colsum_k<<<4, 256, 0, stream>>>(W1, S01);
    w1t_k<<<(H1_ * KE) / 256, 256, 0, stream>>>(W1, W1t);
    transpose_bf16_k<<<(H2_ * H1_ + 255) / 256, 256, 0, stream>>>(W2, W2t, H1_, H2_);

    // fused gather + GEMM1, BM=320/BN=256 (114.5 KB dynamic LDS)
    hipFuncSetAttribute((const void*)fused_gemm1_k,
                        hipFuncAttributeMaxDynamicSharedMemorySize, 117248);
    fused_gemm1_k<<<256, 512, 117248, stream>>>(x_raw, x_idx, emb, W1t, b1, S01, h1);

    // fused GEMM2 + head -> softmax out
    gemm2_head_k<<<256, 512, 0, stream>>>(h1, W2t, b2, W3, b3, (float*)d_out);
}

// Round 9
// 217.964 us; speedup vs baseline: 1.8098x; 1.8098x over previous
//
#include <hip/hip_runtime.h>
#include <hip/hip_bf16.h>
#include <stdint.h>

#define B_   2048
#define P_   20
#define D_   64
#define V_   100000
#define T_   33
#define FIN  2240          // 35*64
#define KE   2112          // 33*64  (emb-only K; raw cols folded into epilogue)
#define M_   (B_*P_)       // 40960
#define H1_  512
#define H2_  256
#define NKT  33            // K-tiles of 64 (two halves of 32)

using bf16 = __hip_bfloat16;
typedef __bf16 bf16x8 __attribute__((ext_vector_type(8)));
typedef float  f32x4  __attribute__((ext_vector_type(4)));

__device__ __forceinline__ void gload16(const void* g, void* l) {
    __builtin_amdgcn_global_load_lds(
        (const __attribute__((address_space(1))) uint32_t*)g,
        (__attribute__((address_space(3))) uint32_t*)l, 16, 0, 0);
}
__device__ __forceinline__ void gload4(const void* g, void* l) {
    __builtin_amdgcn_global_load_lds(
        (const __attribute__((address_space(1))) uint32_t*)g,
        (__attribute__((address_space(3))) uint32_t*)l, 4, 0, 0);
}

// ---------------------------------------------------------------------------
// prep 1: column sums of W1 rows 0..63 (S0) and 64..127 (S1).  S01 = [S0|S1]
// ---------------------------------------------------------------------------
__global__ __launch_bounds__(256) void colsum_k(
    const float* __restrict__ W1, float* __restrict__ S01)
{
    int g = blockIdx.x * 256 + threadIdx.x;   // 0..1023
    int s = g >> 9, n = g & 511;
    const float* p = W1 + (size_t)(s * 64) * H1_ + n;
    float acc = 0.f;
    #pragma unroll 8
    for (int k = 0; k < 64; ++k) acc += p[(size_t)k * H1_];
    S01[s * H1_ + n] = acc;
}

// ---------------------------------------------------------------------------
// prep 2: W1 rows 128.. -> W1t (512 x 2112) bf16 row-major (transposed)
// ---------------------------------------------------------------------------
__global__ __launch_bounds__(256) void w1t_k(
    const float* __restrict__ W1, bf16* __restrict__ W1t)
{
    int idx = blockIdx.x * 256 + threadIdx.x;   // n*KE + k
    int n = idx / KE;
    int k = idx - n * KE;
    W1t[idx] = __float2bfloat16(W1[(size_t)(k + 128) * H1_ + n]);
}

// ---------------------------------------------------------------------------
// prep 3: generic W (K x N fp32) -> Wt (N x K bf16)
// ---------------------------------------------------------------------------
__global__ __launch_bounds__(256) void transpose_bf16_k(
    const float* __restrict__ W, bf16* __restrict__ Wt, int K, int N)
{
    int idx = blockIdx.x * 256 + threadIdx.x;
    if (idx >= N * K) return;
    int n = idx / K;
    int k = idx - n * K;
    Wt[idx] = __float2bfloat16(W[(size_t)k * N + n]);
}

// ---------------------------------------------------------------------------
// FUSED gather + GEMM1 (v9): BM=320, BN=256, ALL-global_load_lds pipeline.
//   grid 256: mt=(bid&7)|((bid>>4)<<3), nt=(bid>>3)&1 -> the two N-halves of
//   an M-tile are bids b,b+8 (same XCD round-robin) so the duplicated
//   A-gather shares L2.  B traffic halved vs R5 (553->277 MB).
//   A: fp32 DIRECT to LDS in two single-buffered 40KB K-halves; each half
//      overwritten right after its MFMA (≈half-iter latency cover).
//   B: two 16KB K-halves, same ping-pong.   idx: LDS ring depth 2.
//   Per-wave in-flight invariant 15; waits vmcnt(7)/vmcnt(8) — never 0 in
//   the main loop.  No VGPR-destined global loads anywhere in the loop
//   (R3/R4/R8 lesson: those trigger compiler auto-drains).
// ---------------------------------------------------------------------------
__global__ __launch_bounds__(512, 2) void fused_gemm1_k(
    const float* __restrict__ x_raw, const int* __restrict__ x_idx,
    const float* __restrict__ emb, const bf16* __restrict__ W1t,
    const float* __restrict__ b1, const float* __restrict__ S01,
    bf16* __restrict__ h1)
{
    extern __shared__ char smem[];
    char* Als  = smem;                   // 2 halves x [320 rows][128B fp32] = 81920
    char* Bls  = smem + 81920;           // 2 halves x [256 rows][64B bf16]  = 32768
    char* ring = smem + 81920 + 32768;   // 2 slots x 8 waves x 160B         = 2560

    const int tid = threadIdx.x;
    const int w  = tid >> 6, l = tid & 63;
    const int wr = w >> 1, wc = w & 1;           // 4M x 2N wave grid
    const int fr = l & 15, fq = l >> 4;

    const int bid = blockIdx.x;
    const int mt  = (bid & 7) | ((bid >> 4) << 3);
    const int nt  = (bid >> 3) & 1;
    const int m0  = mt * 320;
    const int n0  = nt * 256;

    const int ar8 = l >> 3;                      // A: row-in-instr (8 rows)
    const int ac8 = l & 7;                       // A: 16B unit in 128B half-row
    const int br4 = l >> 2;                      // B: row-in-instr (16 rows)
    const int bc4 = l & 3;                       // B: 16B unit in 64B row

    f32x4 acc[5][8] = {};
    int iv[5];

    auto issue_idx = [&](int t) {                // 1 instr/wave, lanes 0..39
        if (l < 40)
            gload4((const char*)x_idx + ((size_t)(m0 + w * 40 + l) * T_ + t) * 4,
                   ring + (t & 1) * 1280 + w * 160);
    };
    auto read_iv = [&](int t) {                  // ds_read own-wave slot
        const int* ivp = (const int*)(ring + (t & 1) * 1280 + w * 160);
        #pragma unroll
        for (int p = 0; p < 5; ++p) iv[p] = ivp[p * 8 + ar8];
    };
    auto issue_A = [&](int t, int h) {           // 5 instr/wave (8 rows each)
        char* dst = Als + h * 40960 + w * 5120;
        #pragma unroll
        for (int p = 0; p < 5; ++p) {
            int row = w * 40 + p * 8 + ar8;
            const char* src = (const char*)(emb + ((size_t)t * V_ + (size_t)iv[p]) * D_)
                              + h * 128 + ((ac8 * 16) ^ ((row & 7) << 4));
            gload16(src, dst + p * 1024);
        }
    };
    auto issue_B = [&](int t, int h) {           // 2 instr/wave (16 rows each)
        char* dst = Bls + h * 16384 + w * 2048;
        #pragma unroll
        for (int i = 0; i < 2; ++i) {
            int row = w * 32 + i * 16 + br4;
            const char* src = (const char*)W1t
                + ((size_t)(n0 + row) * KE + t * 64 + h * 32) * 2
                + ((bc4 * 16) ^ ((row & 3) << 4));
            gload16(src, dst + i * 1024);
        }
    };
    auto mfma_half = [&](int h) {
        const char* Ab = Als + h * 40960;
        bf16x8 af[5];
        #pragma unroll
        for (int i = 0; i < 5; ++i) {
            int r  = wr * 80 + i * 16 + fr;
            int xr = (r & 7) << 4;
            float4 a0 = *(const float4*)(Ab + r * 128 + ((fq * 32) ^ xr));
            float4 a1 = *(const float4*)(Ab + r * 128 + ((fq * 32 + 16) ^ xr));
            bf16x8 t;
            t[0] = (__bf16)a0.x; t[1] = (__bf16)a0.y;
            t[2] = (__bf16)a0.z; t[3] = (__bf16)a0.w;
            t[4] = (__bf16)a1.x; t[5] = (__bf16)a1.y;
            t[6] = (__bf16)a1.z; t[7] = (__bf16)a1.w;
            af[i] = t;
        }
        const char* Bb = Bls + h * 16384;
        #pragma unroll
        for (int j = 0; j < 8; ++j) {
            int n = wc * 128 + j * 16 + fr;
            bf16x8 bg = *(const bf16x8*)(Bb + n * 64 + ((fq * 16) ^ ((n & 3) << 4)));
            #pragma unroll
            for (int i = 0; i < 5; ++i)
                acc[i][j] = __builtin_amdgcn_mfma_f32_16x16x32_bf16(
                    af[i], bg, acc[i][j], 0, 0, 0);
        }
    };

    // ---- prologue -------------------------------------------------------
    issue_idx(0);
    asm volatile("s_waitcnt vmcnt(0)" ::: "memory");
    read_iv(0);
    issue_A(0, 0);                               // +5
    issue_B(0, 0);                               // +2
    issue_idx(1);                                // +1
    issue_A(0, 1);                               // +5
    issue_B(0, 1);                               // +2
    // stack: [Ah0 5, Bh0 2, idx 1, Ah1 5, Bh1 2] = 15  (loop invariant)

    // ---- main loop ------------------------------------------------------
    for (int kt = 0; kt < NKT; ++kt) {
        int tA = (kt + 1 < NKT) ? kt + 1 : NKT - 1;   // clamped tail keeps
        int t2 = (kt + 2 < NKT) ? kt + 2 : NKT - 1;   // counts uniform

        asm volatile("s_waitcnt vmcnt(7)" ::: "memory");   // Ah0,Bh0,idx done
        read_iv(tA);                                       // iv for tA issues
        __builtin_amdgcn_s_barrier();
        __builtin_amdgcn_sched_barrier(0);

        __builtin_amdgcn_s_setprio(1);
        mfma_half(0);
        __builtin_amdgcn_s_setprio(0);
        asm volatile("s_waitcnt lgkmcnt(0)" ::: "memory"); // LDS reads retired
        __builtin_amdgcn_s_barrier();

        issue_A(tA, 0);                                    // +5 (overwrite Ah0)
        issue_B(tA, 0);                                    // +2 (overwrite Bh0)
        issue_idx(t2);                                     // +1
        asm volatile("s_waitcnt vmcnt(8)" ::: "memory");   // Ah1,Bh1 done
        __builtin_amdgcn_s_barrier();
        __builtin_amdgcn_sched_barrier(0);

        __builtin_amdgcn_s_setprio(1);
        mfma_half(1);
        __builtin_amdgcn_s_setprio(0);
        asm volatile("s_waitcnt lgkmcnt(0)" ::: "memory");
        __builtin_amdgcn_s_barrier();

        issue_A(tA, 1);                                    // +5 (overwrite Ah1)
        issue_B(tA, 1);                                    // +2 (overwrite Bh1)
        // stack back to [Ah0 5, Bh0 2, idx 1, Ah1 5, Bh1 2] = 15
    }
    asm volatile("s_waitcnt vmcnt(0)" ::: "memory");       // drain clamped junk

    // ---- epilogue: bias + rank-2 raw contribution + relu -> h1 ---------
    const float* S0 = S01;
    const float* S1 = S01 + H1_;
    #pragma unroll
    for (int i = 0; i < 5; ++i) {
        int rbase = wr * 80 + i * 16 + fq * 4;
        float x0[4], x1[4];
        #pragma unroll
        for (int r2 = 0; r2 < 4; ++r2) {
            int m = m0 + rbase + r2;
            x0[r2] = x_raw[2 * m];
            x1[r2] = x_raw[2 * m + 1];
        }
        #pragma unroll
        for (int j = 0; j < 8; ++j) {
            int n = n0 + wc * 128 + j * 16 + fr;
            float bb = b1[n], s0 = S0[n], s1 = S1[n];
            #pragma unroll
            for (int r2 = 0; r2 < 4; ++r2) {
                float v = acc[i][j][r2] + bb + x0[r2] * s0 + x1[r2] * s1;
                h1[(size_t)(m0 + rbase + r2) * H1_ + n] =
                    __float2bfloat16(fmaxf(v, 0.0f));
            }
        }
    }
}

// ---------------------------------------------------------------------------
// FUSED GEMM2 + head (R3/R5-proven):  h2 = relu(h1 @ W2 + b2);
// logits = h2 @ W3 + b3; softmax over P=20.  BM=160 (=8 batches), BN=256.
// ---------------------------------------------------------------------------
__global__ __launch_bounds__(512) void gemm2_head_k(
    const bf16* __restrict__ h1, const bf16* __restrict__ W2t,
    const float* __restrict__ b2, const float* __restrict__ W3,
    const float* __restrict__ b3, float* __restrict__ out)
{
    __shared__ char  As[20480];       // [160][64] bf16 swizzled
    __shared__ char  Bs[32768];       // [256][64] bf16 swizzled
    __shared__ float w3s[H2_];
    __shared__ float b2s[H2_];
    __shared__ float logq[4][160];
    __shared__ float logits[160];

    const int tid = threadIdx.x;
    const int w = tid >> 6, l = tid & 63;
    const int wr = w >> 2, wc = w & 3;
    const int fr = l & 15, fq = l >> 4;
    const int m0 = blockIdx.x * 160;
    const int r8 = l >> 3, c8 = l & 7;

    if (tid < H2_) { w3s[tid] = W3[tid]; b2s[tid] = b2[tid]; }

    f32x4 acc[5][4] = {};

    for (int kt = 0; kt < 8; ++kt) {
        for (int s = w; s < 20; s += 8) {
            int row = s * 8 + r8;
            const char* src = (const char*)(h1 + (size_t)(m0 + row) * H1_ + kt * 64)
                              + ((16 * c8) ^ ((row & 7) << 4));
            gload16(src, As + s * 1024);
        }
        #pragma unroll
        for (int q = 0; q < 4; ++q) {
            int s = q * 8 + w;
            int row = s * 8 + r8;
            const char* src = (const char*)(W2t + (size_t)row * H1_ + kt * 64)
                              + ((16 * c8) ^ ((row & 7) << 4));
            gload16(src, Bs + s * 1024);
        }
        __syncthreads();

        #pragma unroll
        for (int kk = 0; kk < 2; ++kk) {
            bf16x8 af[5];
            #pragma unroll
            for (int i = 0; i < 5; ++i) {
                int r = wr * 80 + i * 16 + fr;
                int byte = (r * 128 + kk * 64 + fq * 16) ^ ((r & 7) << 4);
                af[i] = *(const bf16x8*)(As + byte);
            }
            #pragma unroll
            for (int j = 0; j < 4; ++j) {
                int n = wc * 64 + j * 16 + fr;
                int byte = (n * 128 + kk * 64 + fq * 16) ^ ((n & 7) << 4);
                bf16x8 bg = *(const bf16x8*)(Bs + byte);
                #pragma unroll
                for (int i = 0; i < 5; ++i)
                    acc[i][j] = __builtin_amdgcn_mfma_f32_16x16x32_bf16(
                        af[i], bg, acc[i][j], 0, 0, 0);
            }
        }
        __syncthreads();
    }

    #pragma unroll
    for (int i = 0; i < 5; ++i) {
        #pragma unroll
        for (int r2 = 0; r2 < 4; ++r2) {
            float s = 0.f;
            #pragma unroll
            for (int j = 0; j < 4; ++j) {
                int col = wc * 64 + j * 16 + fr;
                float v = fmaxf(acc[i][j][r2] + b2s[col], 0.f);
                s += v * w3s[col];
            }
            #pragma unroll
            for (int off = 1; off < 16; off <<= 1) s += __shfl_xor(s, off);
            if (fr == 0)
                logq[wc][wr * 80 + i * 16 + fq * 4 + r2] = s;
        }
    }
    __syncthreads();
    if (tid < 160)
        logits[tid] = logq[0][tid] + logq[1][tid] + logq[2][tid] + logq[3][tid] + b3[0];
    __syncthreads();
    if (tid < 160) {
        int bb = (tid / 20) * 20;
        float mx = -1e30f;
        #pragma unroll
        for (int p = 0; p < 20; ++p) mx = fmaxf(mx, logits[bb + p]);
        float sum = 0.f;
        #pragma unroll
        for (int p = 0; p < 20; ++p) sum += expf(logits[bb + p] - mx);
        out[m0 + tid] = expf(logits[tid] - mx) / sum;
    }
}

// ---------------------------------------------------------------------------
extern "C" void kernel_launch(void* const* d_in, const int* in_sizes, int n_in,
                              void* d_out, int out_size, void* d_ws, size_t ws_size,
                              hipStream_t stream)
{
    const float* x_raw = (const float*)d_in[0];
    const int*   x_idx = (const int*)  d_in[1];
    const float* emb   = (const float*)d_in[2];
    const float* W1    = (const float*)d_in[3];
    const float* b1    = (const float*)d_in[4];
    const float* W2    = (const float*)d_in[5];
    const float* b2    = (const float*)d_in[6];
    const float* W3    = (const float*)d_in[7];
    const float* b3    = (const float*)d_in[8];

    char* ws = (char*)d_ws;
    size_t off = 0;
    bf16*  W1t = (bf16*) (ws + off); off += (size_t)H1_ * KE * 2;    // 2.16 MB
    bf16*  W2t = (bf16*) (ws + off); off += (size_t)H2_ * H1_ * 2;   // 0.26 MB
    float* S01 = (float*)(ws + off); off += (size_t)2 * H1_ * 4;     // 4 KB
    bf16*  h1  = (bf16*) (ws + off); off += (size_t)M_ * H1_ * 2;    // 42 MB

    // prep
    colsum_k<<<4, 256, 0, stream>>>(W1, S01);
    w1t_k<<<(H1_ * KE) / 256, 256, 0, stream>>>(W1, W1t);
    transpose_bf16_k<<<(H2_ * H1_ + 255) / 256, 256, 0, stream>>>(W2, W2t, H1_, H2_);

    // fused gather + GEMM1, BM=320/BN=256, all-gload_lds (114.5 KB LDS)
    hipFuncSetAttribute((const void*)fused_gemm1_k,
                        hipFuncAttributeMaxDynamicSharedMemorySize, 117248);
    fused_gemm1_k<<<256, 512, 117248, stream>>>(x_raw, x_idx, emb, W1t, b1, S01, h1);

    // fused GEMM2 + head -> softmax out
    gemm2_head_k<<<256, 512, 0, stream>>>(h1, W2t, b2, W3, b3, (float*)d_out);
}

// Round 11
// 189.181 us; speedup vs baseline: 2.0851x; 1.1521x over previous
//
#include <hip/hip_runtime.h>
#include <hip/hip_bf16.h>
#include <stdint.h>

#define B_   2048
#define P_   20
#define D_   64
#define V_   100000
#define T_   33
#define FIN  2240          // 35*64
#define KE   2112          // 33*64  (emb-only K; raw cols folded into epilogue)
#define M_   (B_*P_)       // 40960
#define H1_  512
#define H2_  256
#define NKT  33            // K-tiles of 64

using bf16 = __hip_bfloat16;
typedef __bf16 bf16x8 __attribute__((ext_vector_type(8)));
typedef float  f32x4  __attribute__((ext_vector_type(4)));

__device__ __forceinline__ void gload16(const void* g, void* l) {
    __builtin_amdgcn_global_load_lds(
        (const __attribute__((address_space(1))) uint32_t*)g,
        (__attribute__((address_space(3))) uint32_t*)l, 16, 0, 0);
}
__device__ __forceinline__ void gload4(const void* g, void* l) {
    __builtin_amdgcn_global_load_lds(
        (const __attribute__((address_space(1))) uint32_t*)g,
        (__attribute__((address_space(3))) uint32_t*)l, 4, 0, 0);
}

// ---------------------------------------------------------------------------
// prep 1: column sums of W1 rows 0..63 (S0) and 64..127 (S1).  S01 = [S0|S1]
// ---------------------------------------------------------------------------
__global__ __launch_bounds__(256) void colsum_k(
    const float* __restrict__ W1, float* __restrict__ S01)
{
    int g = blockIdx.x * 256 + threadIdx.x;   // 0..1023
    int s = g >> 9, n = g & 511;
    const float* p = W1 + (size_t)(s * 64) * H1_ + n;
    float acc = 0.f;
    #pragma unroll 8
    for (int k = 0; k < 64; ++k) acc += p[(size_t)k * H1_];
    S01[s * H1_ + n] = acc;
}

// ---------------------------------------------------------------------------
// prep 2: W1 rows 128.. -> W1t (512 x 2112) bf16 row-major (transposed)
// ---------------------------------------------------------------------------
__global__ __launch_bounds__(256) void w1t_k(
    const float* __restrict__ W1, bf16* __restrict__ W1t)
{
    int idx = blockIdx.x * 256 + threadIdx.x;   // n*KE + k
    int n = idx / KE;
    int k = idx - n * KE;
    W1t[idx] = __float2bfloat16(W1[(size_t)(k + 128) * H1_ + n]);
}

// ---------------------------------------------------------------------------
// prep 3: generic W (K x N fp32) -> Wt (N x K bf16)
// ---------------------------------------------------------------------------
__global__ __launch_bounds__(256) void transpose_bf16_k(
    const float* __restrict__ W, bf16* __restrict__ Wt, int K, int N)
{
    int idx = blockIdx.x * 256 + threadIdx.x;
    if (idx >= N * K) return;
    int n = idx / K;
    int k = idx - n * K;
    Wt[idx] = __float2bfloat16(W[(size_t)k * N + n]);
}

// ---------------------------------------------------------------------------
// FUSED gather + GEMM1 (v11 = R5's v5 VERBATIM + per-block K-rotation):
//   h1 = relu(feat @ W1 + b1).  grid 256 (BM=160), 512 thr = 8 waves (2x4).
//   ALL main-loop global traffic is global_load_lds; manual counted vmcnt
//   is authoritative.  Per-wave in-flight invariant: 5 A + 1 idx + 4 + 4 B.
//   K-ROTATION (only diff vs R5): block starts its K-loop at kt0 = bid % 33
//   and wraps: tile(s) = (kt0+s) % 33.  The ~32 blocks of an XCD then read
//   32 DISTINCT B tiles at any instant -> the XCD's B working set is all of
//   W1t (2.1 MB < 4 MB L2) with every tile re-touched every step -> W1t
//   stays L2-resident instead of 553 MB of HBM re-fetch.  No tail clamp
//   needed: wrapping keeps issue counts uniform; wrapped re-issues land in
//   buffers never consumed and are drained by the final vmcnt(0).
// ---------------------------------------------------------------------------
__global__ __launch_bounds__(512, 2) void fused_gemm1_k(
    const float* __restrict__ x_raw, const int* __restrict__ x_idx,
    const float* __restrict__ emb, const bf16* __restrict__ W1t,
    const float* __restrict__ b1, const float* __restrict__ S01,
    bf16* __restrict__ h1)
{
    extern __shared__ char smem[];
    char* Als  = smem;                  // 2 x [160 rows][256B fp32] = 81920
    char* Bls  = smem + 81920;          // 2 halves x [512 rows][64B bf16] = 65536
    char* ring = smem + 81920 + 65536;  // 2 slots x 8 waves x 80B = 1280

    const int tid = threadIdx.x;
    const int w  = tid >> 6, l = tid & 63;
    const int wr = w >> 2, wc = w & 3;          // 2 x 4 wave grid
    const int fr = l & 15, fq = l >> 4;
    const int m0 = blockIdx.x * 160;

    const int arow_sub = l >> 4;                // 0..3   (A: 4 rows/instr)
    const int acol     = l & 15;                // 16B unit within 256B row
    const int brow_sub = l >> 2;                // 0..15  (B: 16 rows/instr)
    const int bcol     = l & 3;                 // 16B unit within 64B row

    f32x4 acc[5][8] = {};
    int iv[5];

    const int kt0 = (int)blockIdx.x % NKT;
    auto tile = [&](int s) { int t = kt0 + s; while (t >= NKT) t -= NKT; return t; };

    auto issue_idx = [&](int t, int slot) {     // 1 instr/wave (lanes 0..19)
        if (l < 20)
            gload4((const char*)x_idx + ((size_t)(m0 + w * 20 + l) * T_ + t) * 4,
                   ring + slot * 640 + w * 80);
    };
    auto issue_A = [&](int t, int buf) {        // 5 instr/wave
        char* dst = Als + buf * 40960 + (w * 20) * 256;
        #pragma unroll
        for (int p = 0; p < 5; ++p) {
            int row = w * 20 + p * 4 + arow_sub;
            const char* src = (const char*)(emb + ((size_t)t * V_ + (size_t)iv[p]) * D_)
                              + ((acol * 16) ^ ((row & 7) << 4));
            gload16(src, dst + p * 1024);
        }
    };
    auto issue_B = [&](int t, int h) {          // 4 instr/wave
        char* dst = Bls + h * 32768 + w * 4096;
        #pragma unroll
        for (int i = 0; i < 4; ++i) {
            int row = w * 64 + i * 16 + brow_sub;
            const char* src = (const char*)W1t + ((size_t)row * KE + t * 64 + h * 32) * 2
                              + ((bcol * 16) ^ ((row & 3) << 4));
            gload16(src, dst + i * 1024);
        }
    };
    auto read_iv = [&](int slot) {
        const int* ivp = (const int*)(ring + slot * 640 + w * 80);
        #pragma unroll
        for (int p = 0; p < 5; ++p) iv[p] = ivp[p * 4 + arow_sub];
    };
    auto mfma_half = [&](int abuf, int kk) {
        const char* Ab = Als + abuf * 40960;
        bf16x8 af[5];
        #pragma unroll
        for (int i = 0; i < 5; ++i) {
            int r  = wr * 80 + i * 16 + fr;
            int xr = (r & 7) << 4;
            float4 a0 = *(const float4*)(Ab + r * 256 + ((kk * 128 + fq * 32) ^ xr));
            float4 a1 = *(const float4*)(Ab + r * 256 + ((kk * 128 + fq * 32 + 16) ^ xr));
            bf16x8 t;
            t[0] = (__bf16)a0.x; t[1] = (__bf16)a0.y;
            t[2] = (__bf16)a0.z; t[3] = (__bf16)a0.w;
            t[4] = (__bf16)a1.x; t[5] = (__bf16)a1.y;
            t[6] = (__bf16)a1.z; t[7] = (__bf16)a1.w;
            af[i] = t;
        }
        const char* Bb = Bls + kk * 32768;
        #pragma unroll
        for (int j = 0; j < 8; ++j) {
            int n = wc * 128 + j * 16 + fr;
            bf16x8 bg = *(const bf16x8*)(Bb + n * 64 + ((fq * 16) ^ ((n & 3) << 4)));
            #pragma unroll
            for (int i = 0; i < 5; ++i)
                acc[i][j] = __builtin_amdgcn_mfma_f32_16x16x32_bf16(
                    af[i], bg, acc[i][j], 0, 0, 0);
        }
    };

    // ---- prologue -------------------------------------------------------
    issue_idx(tile(0), 0);
    asm volatile("s_waitcnt vmcnt(0)" ::: "memory");
    read_iv(0);
    issue_A(tile(0), 0);                          // +5
    issue_idx(tile(1), 1);                        // +1
    issue_B(tile(0), 0);                          // +4
    issue_B(tile(0), 1);                          // +4
    // in-flight stack: [A 5, idx 1, Bh0 4, Bh1 4] = 14  (steady invariant)

    // ---- main loop ------------------------------------------------------
    for (int s = 0; s < NKT; ++s) {
        int tA = tile(s + 1);                     // wraps; no clamp needed
        int t2 = tile(s + 2);

        asm volatile("s_waitcnt vmcnt(8)" ::: "memory");   // idx(s+1), A(s) done
        read_iv((s + 1) & 1);
        issue_A(tA, (s + 1) & 1);                          // +5
        issue_idx(t2, s & 1);                              // +1
        asm volatile("s_waitcnt vmcnt(10)" ::: "memory");  // B(s,h0) done
        __builtin_amdgcn_s_barrier();
        __builtin_amdgcn_sched_barrier(0);

        __builtin_amdgcn_s_setprio(1);
        mfma_half(s & 1, 0);
        __builtin_amdgcn_s_setprio(0);
        asm volatile("s_waitcnt lgkmcnt(0)" ::: "memory"); // LDS reads retired
        __builtin_amdgcn_s_barrier();

        issue_B(tA, 0);                                    // +4 (overwrite Bh0)
        asm volatile("s_waitcnt vmcnt(10)" ::: "memory");  // B(s,h1) done
        __builtin_amdgcn_s_barrier();
        __builtin_amdgcn_sched_barrier(0);

        __builtin_amdgcn_s_setprio(1);
        mfma_half(s & 1, 1);
        __builtin_amdgcn_s_setprio(0);
        asm volatile("s_waitcnt lgkmcnt(0)" ::: "memory");
        __builtin_amdgcn_s_barrier();

        issue_B(tA, 1);                                    // +4 (overwrite Bh1)
        // stack back to [A 5, idx 1, Bh0 4, Bh1 4] = 14
    }
    asm volatile("s_waitcnt vmcnt(0)" ::: "memory");       // drain wrapped junk

    // ---- epilogue: bias + rank-2 raw contribution + relu -> h1 ---------
    const float* S0 = S01;
    const float* S1 = S01 + H1_;
    #pragma unroll
    for (int i = 0; i < 5; ++i) {
        int rbase = wr * 80 + i * 16 + fq * 4;
        float x0[4], x1[4];
        #pragma unroll
        for (int r2 = 0; r2 < 4; ++r2) {
            int m = m0 + rbase + r2;
            x0[r2] = x_raw[2 * m];
            x1[r2] = x_raw[2 * m + 1];
        }
        #pragma unroll
        for (int j = 0; j < 8; ++j) {
            int n = wc * 128 + j * 16 + fr;
            float bb = b1[n], s0 = S0[n], s1 = S1[n];
            #pragma unroll
            for (int r2 = 0; r2 < 4; ++r2) {
                float v = acc[i][j][r2] + bb + x0[r2] * s0 + x1[r2] * s1;
                h1[(size_t)(m0 + rbase + r2) * H1_ + n] =
                    __float2bfloat16(fmaxf(v, 0.0f));
            }
        }
    }
}

// ---------------------------------------------------------------------------
// FUSED GEMM2 + head (R3/R5-proven):  h2 = relu(h1 @ W2 + b2);
// logits = h2 @ W3 + b3; softmax over P=20.  BM=160 (=8 batches), BN=256.
// ---------------------------------------------------------------------------
__global__ __launch_bounds__(512) void gemm2_head_k(
    const bf16* __restrict__ h1, const bf16* __restrict__ W2t,
    const float* __restrict__ b2, const float* __restrict__ W3,
    const float* __restrict__ b3, float* __restrict__ out)
{
    __shared__ char  As[20480];       // [160][64] bf16 swizzled
    __shared__ char  Bs[32768];       // [256][64] bf16 swizzled
    __shared__ float w3s[H2_];
    __shared__ float b2s[H2_];
    __shared__ float logq[4][160];
    __shared__ float logits[160];

    const int tid = threadIdx.x;
    const int w = tid >> 6, l = tid & 63;
    const int wr = w >> 2, wc = w & 3;
    const int fr = l & 15, fq = l >> 4;
    const int m0 = blockIdx.x * 160;
    const int r8 = l >> 3, c8 = l & 7;

    if (tid < H2_) { w3s[tid] = W3[tid]; b2s[tid] = b2[tid]; }

    f32x4 acc[5][4] = {};

    for (int kt = 0; kt < 8; ++kt) {
        for (int s = w; s < 20; s += 8) {
            int row = s * 8 + r8;
            const char* src = (const char*)(h1 + (size_t)(m0 + row) * H1_ + kt * 64)
                              + ((16 * c8) ^ ((row & 7) << 4));
            gload16(src, As + s * 1024);
        }
        #pragma unroll
        for (int q = 0; q < 4; ++q) {
            int s = q * 8 + w;
            int row = s * 8 + r8;
            const char* src = (const char*)(W2t + (size_t)row * H1_ + kt * 64)
                              + ((16 * c8) ^ ((row & 7) << 4));
            gload16(src, Bs + s * 1024);
        }
        __syncthreads();

        #pragma unroll
        for (int kk = 0; kk < 2; ++kk) {
            bf16x8 af[5];
            #pragma unroll
            for (int i = 0; i < 5; ++i) {
                int r = wr * 80 + i * 16 + fr;
                int byte = (r * 128 + kk * 64 + fq * 16) ^ ((r & 7) << 4);
                af[i] = *(const bf16x8*)(As + byte);
            }
            #pragma unroll
            for (int j = 0; j < 4; ++j) {
                int n = wc * 64 + j * 16 + fr;
                int byte = (n * 128 + kk * 64 + fq * 16) ^ ((n & 7) << 4);
                bf16x8 bg = *(const bf16x8*)(Bs + byte);
                #pragma unroll
                for (int i = 0; i < 5; ++i)
                    acc[i][j] = __builtin_amdgcn_mfma_f32_16x16x32_bf16(
                        af[i], bg, acc[i][j], 0, 0, 0);
            }
        }
        __syncthreads();
    }

    #pragma unroll
    for (int i = 0; i < 5; ++i) {
        #pragma unroll
        for (int r2 = 0; r2 < 4; ++r2) {
            float s = 0.f;
            #pragma unroll
            for (int j = 0; j < 4; ++j) {
                int col = wc * 64 + j * 16 + fr;
                float v = fmaxf(acc[i][j][r2] + b2s[col], 0.f);
                s += v * w3s[col];
            }
            #pragma unroll
            for (int off = 1; off < 16; off <<= 1) s += __shfl_xor(s, off);
            if (fr == 0)
                logq[wc][wr * 80 + i * 16 + fq * 4 + r2] = s;
        }
    }
    __syncthreads();
    if (tid < 160)
        logits[tid] = logq[0][tid] + logq[1][tid] + logq[2][tid] + logq[3][tid] + b3[0];
    __syncthreads();
    if (tid < 160) {
        int bb = (tid / 20) * 20;
        float mx = -1e30f;
        #pragma unroll
        for (int p = 0; p < 20; ++p) mx = fmaxf(mx, logits[bb + p]);
        float sum = 0.f;
        #pragma unroll
        for (int p = 0; p < 20; ++p) sum += expf(logits[bb + p] - mx);
        out[m0 + tid] = expf(logits[tid] - mx) / sum;
    }
}

// ---------------------------------------------------------------------------
extern "C" void kernel_launch(void* const* d_in, const int* in_sizes, int n_in,
                              void* d_out, int out_size, void* d_ws, size_t ws_size,
                              hipStream_t stream)
{
    const float* x_raw = (const float*)d_in[0];
    const int*   x_idx = (const int*)  d_in[1];
    const float* emb   = (const float*)d_in[2];
    const float* W1    = (const float*)d_in[3];
    const float* b1    = (const float*)d_in[4];
    const float* W2    = (const float*)d_in[5];
    const float* b2    = (const float*)d_in[6];
    const float* W3    = (const float*)d_in[7];
    const float* b3    = (const float*)d_in[8];

    char* ws = (char*)d_ws;
    size_t off = 0;
    bf16*  W1t = (bf16*) (ws + off); off += (size_t)H1_ * KE * 2;    // 2.16 MB
    bf16*  W2t = (bf16*) (ws + off); off += (size_t)H2_ * H1_ * 2;   // 0.26 MB
    float* S01 = (float*)(ws + off); off += (size_t)2 * H1_ * 4;     // 4 KB
    bf16*  h1  = (bf16*) (ws + off); off += (size_t)M_ * H1_ * 2;    // 42 MB

    // prep
    colsum_k<<<4, 256, 0, stream>>>(W1, S01);
    w1t_k<<<(H1_ * KE) / 256, 256, 0, stream>>>(W1, W1t);
    transpose_bf16_k<<<(H2_ * H1_ + 255) / 256, 256, 0, stream>>>(W2, W2t, H1_, H2_);

    // fused gather + GEMM1 (145.25 KB dynamic LDS)
    hipFuncSetAttribute((const void*)fused_gemm1_k,
                        hipFuncAttributeMaxDynamicSharedMemorySize, 148736);
    fused_gemm1_k<<<256, 512, 148736, stream>>>(x_raw, x_idx, emb, W1t, b1, S01, h1);

    // fused GEMM2 + head -> softmax out
    gemm2_head_k<<<256, 512, 0, stream>>>(h1, W2t, b2, W3, b3, (float*)d_out);
}